// Round 1
// baseline (48.580 us; speedup 1.0000x reference)
//
#include <hip/hip_runtime.h>
#include <hip/hip_bf16.h>

// ---------------------------------------------------------------------------
// PointNet2 FP module: knn(k=3) interpolate -> concat -> 2x (GEMM+bias+ReLU)
// B=16, N_in=4096 (256/batch), N_skip=16384 (1024/batch), C_in=256, C_skip=128
// H = [16384, 416] bf16  (387 real cols: interp|skip_x|pos, padded w/ zeros)
// ---------------------------------------------------------------------------

typedef __bf16 bf16x8 __attribute__((ext_vector_type(8)));
typedef float  f32x4  __attribute__((ext_vector_type(4)));

__device__ __forceinline__ unsigned short f2bf(float f) {
  __hip_bfloat16 h = __float2bfloat16(f);
  return __builtin_bit_cast(unsigned short, h);
}

#define GLDS16(G, L)                                                          \
  __builtin_amdgcn_global_load_lds(                                           \
      (const __attribute__((address_space(1))) void*)(G),                     \
      (__attribute__((address_space(3))) void*)(L), 16, 0, 0)

static constexpr int MROWS  = 16384;   // skip points
static constexpr int KPAD   = 416;     // 387 padded to 13*32
static constexpr int KREAL  = 387;

// ---------------- weight prep: W1t[256][416], W2t[256][256] bf16 -----------
__global__ __launch_bounds__(256) void prep_weights(
    const float* __restrict__ W1, const float* __restrict__ W2,
    unsigned short* __restrict__ W1t, unsigned short* __restrict__ W2t)
{
  const int k = blockIdx.x;    // 0..415
  const int n = threadIdx.x;   // 0..255
  {
    float v = (k < KREAL) ? W1[(size_t)k * 256 + n] : 0.f;
    W1t[(size_t)n * KPAD + k] = f2bf(v);
  }
  if (k < 256) {
    W2t[(size_t)n * 256 + k] = f2bf(W2[(size_t)k * 256 + n]);
  }
}

// ---------------- knn(k=3) + interpolate + concat -> H bf16 ----------------
// one wave per skip point; 4 skip points / block (all in one batch)
__global__ __launch_bounds__(256) void knn_build_h(
    const float* __restrict__ in_x,      // [4096, 256]
    const float* __restrict__ in_pos,    // [4096, 3]
    const float* __restrict__ skip_x,    // [16384, 128]
    const float* __restrict__ skip_pos,  // [16384, 3]
    unsigned short* __restrict__ H)      // [16384, 416] bf16
{
  __shared__ float P[3][256];            // batch in_pos, SoA
  const int tid = threadIdx.x;
  const int s0  = blockIdx.x << 2;       // first skip point of block
  const int ib  = (s0 >> 10) << 8;       // first in-point of batch
  {
    const float* bp = in_pos + (size_t)ib * 3;
    for (int i = tid; i < 768; i += 256) P[i % 3][i / 3] = bp[i];
  }
  __syncthreads();

  const int wid = tid >> 6, lane = tid & 63;
  const int s = s0 + wid;
  const float sx = skip_pos[(size_t)s * 3 + 0];
  const float sy = skip_pos[(size_t)s * 3 + 1];
  const float sz = skip_pos[(size_t)s * 3 + 2];

  // d2 in numpy op-order (no fma contraction) so selection matches reference
  float d2[4];
#pragma unroll
  for (int q = 0; q < 4; ++q) {
    const int i = lane + (q << 6);
    const float dx = __fsub_rn(sx, P[0][i]);
    const float dy = __fsub_rn(sy, P[1][i]);
    const float dz = __fsub_rn(sz, P[2][i]);
    d2[q] = __fadd_rn(__fadd_rn(__fmul_rn(dx, dx), __fmul_rn(dy, dy)),
                      __fmul_rn(dz, dz));
  }

  int   gsel[3];
  float wsel[3];
  float wsum = 0.f;
#pragma unroll
  for (int p = 0; p < 3; ++p) {
    float bd = d2[0];
    int   bi = lane;
#pragma unroll
    for (int q = 1; q < 4; ++q) {
      const int i = lane + (q << 6);
      if (d2[q] < bd) { bd = d2[q]; bi = i; }
    }
#pragma unroll
    for (int m = 1; m < 64; m <<= 1) {   // full-wave argmin butterfly
      const float od = __shfl_xor(bd, m);
      const int   oi = __shfl_xor(bi, m);
      if (od < bd || (od == bd && oi < bi)) { bd = od; bi = oi; }
    }
    if ((bi & 63) == lane) d2[bi >> 6] = 3.4e38f;  // remove winner
    gsel[p] = bi;
    // weights from fp32 recompute (matches reference's second dist pass)
    const float dx = __fsub_rn(P[0][bi], sx);
    const float dy = __fsub_rn(P[1][bi], sy);
    const float dz = __fsub_rn(P[2][bi], sz);
    float dist = sqrtf(__fadd_rn(__fadd_rn(__fmul_rn(dx, dx), __fmul_rn(dy, dy)),
                                 __fmul_rn(dz, dz)));
    dist = fmaxf(dist, 1e-10f);
    const float w = 1.0f / dist;
    wsel[p] = w;
    wsum += w;
  }
  const float denom = wsum + 1e-16f;
  const float w0 = wsel[0] / denom;
  const float w1 = wsel[1] / denom;
  const float w2 = wsel[2] / denom;

  // interpolate 256 channels: 4 per lane, float4 loads
  const f32x4* x0 = (const f32x4*)(in_x + (size_t)(ib + gsel[0]) * 256);
  const f32x4* x1 = (const f32x4*)(in_x + (size_t)(ib + gsel[1]) * 256);
  const f32x4* x2 = (const f32x4*)(in_x + (size_t)(ib + gsel[2]) * 256);
  const f32x4 a = x0[lane], b = x1[lane], c = x2[lane];

  unsigned short* hr = H + (size_t)s * KPAD;
  ushort4 o4;
  o4.x = f2bf(w0 * a.x + w1 * b.x + w2 * c.x);
  o4.y = f2bf(w0 * a.y + w1 * b.y + w2 * c.y);
  o4.z = f2bf(w0 * a.z + w1 * b.z + w2 * c.z);
  o4.w = f2bf(w0 * a.w + w1 * b.w + w2 * c.w);
  *(ushort4*)(hr + (lane << 2)) = o4;

  // skip_x: 2 channels per lane
  const float2 sv = ((const float2*)(skip_x + (size_t)s * 128))[lane];
  ushort2 o2;
  o2.x = f2bf(sv.x);
  o2.y = f2bf(sv.y);
  *(ushort2*)(hr + 256 + (lane << 1)) = o2;

  // pos (3) + zero pad to 416
  if (lane < 32) {
    float v = (lane == 0) ? sx : (lane == 1) ? sy : (lane == 2) ? sz : 0.f;
    hr[384 + lane] = f2bf(v);
  }
}

// ---------------- GEMM: C = relu(A[M,K] * Bt[256,K]^T + bias) --------------
// m97 structure: 128x128 tile, BK=32, global_load_lds(16B), 4 waves x (4x4)
template <int K, bool OUT_BF16>
__global__ __launch_bounds__(256) void gemm_bt_relu(
    const unsigned short* __restrict__ A,   // [M, K] bf16
    const unsigned short* __restrict__ Bt,  // [256, K] bf16 (B transposed)
    const float* __restrict__ bias,         // [256]
    void* __restrict__ Out)                 // [M, 256] bf16 or f32
{
  __shared__ unsigned short As[128 * 32];
  __shared__ unsigned short Bs[128 * 32];
  const int tid = threadIdx.x, lane = tid & 63, wid = tid >> 6;
  const int m0 = blockIdx.x << 7, n0 = blockIdx.y << 7;

  // staging: thread t -> tile row t/4, k-offset (t%4)*8; LDS is linear t*16B
  const int srow = tid >> 2;
  const int scol = (tid & 3) << 3;
  const unsigned short* gA0 = A + (size_t)(m0 + srow) * K + scol;
  const unsigned short* gA1 = gA0 + (size_t)64 * K;
  const unsigned short* gB0 = Bt + (size_t)(n0 + srow) * K + scol;
  const unsigned short* gB1 = gB0 + (size_t)64 * K;
  unsigned short* lA0 = As + wid * 512;          // wave-uniform LDS bases
  unsigned short* lA1 = As + 2048 + wid * 512;
  unsigned short* lB0 = Bs + wid * 512;
  unsigned short* lB1 = Bs + 2048 + wid * 512;

  const int wr = (wid >> 1) << 6;   // wave tile: 64x64
  const int wc = (wid & 1) << 6;
  const int fr = lane & 15;
  const int ko = (lane >> 4) << 3;

  f32x4 acc[4][4] = {};

  for (int ks = 0; ks < K / 32; ++ks) {
    const int k0 = ks << 5;
    GLDS16(gA0 + k0, lA0);
    GLDS16(gA1 + k0, lA1);
    GLDS16(gB0 + k0, lB0);
    GLDS16(gB1 + k0, lB1);
    __syncthreads();   // vmcnt drained before barrier -> tiles ready
    bf16x8 af[4], bf[4];
#pragma unroll
    for (int m = 0; m < 4; ++m)
      af[m] = *(const bf16x8*)&As[(wr + m * 16 + fr) * 32 + ko];
#pragma unroll
    for (int n = 0; n < 4; ++n)
      bf[n] = *(const bf16x8*)&Bs[(wc + n * 16 + fr) * 32 + ko];
#pragma unroll
    for (int m = 0; m < 4; ++m)
#pragma unroll
      for (int n = 0; n < 4; ++n)
        acc[m][n] =
            __builtin_amdgcn_mfma_f32_16x16x32_bf16(af[m], bf[n], acc[m][n], 0, 0, 0);
    __syncthreads();   // all waves done reading before next stage
  }

  // epilogue: C/D layout col=lane&15, row=(lane>>4)*4+j  [m89-verified]
  const int r0 = m0 + wr + ((lane >> 4) << 2);
  const int c0 = n0 + wc + fr;
  float bn[4];
#pragma unroll
  for (int n = 0; n < 4; ++n) bn[n] = bias[c0 + n * 16];
#pragma unroll
  for (int m = 0; m < 4; ++m) {
#pragma unroll
    for (int j = 0; j < 4; ++j) {
      const size_t row = (size_t)(r0 + m * 16 + j);
#pragma unroll
      for (int n = 0; n < 4; ++n) {
        const float v = fmaxf(acc[m][n][j] + bn[n], 0.f);
        if constexpr (OUT_BF16)
          ((unsigned short*)Out)[row * 256 + c0 + n * 16] = f2bf(v);
        else
          ((float*)Out)[row * 256 + c0 + n * 16] = v;
      }
    }
  }
}

// ---------------------------------------------------------------------------
extern "C" void kernel_launch(void* const* d_in, const int* in_sizes, int n_in,
                              void* d_out, int out_size, void* d_ws, size_t ws_size,
                              hipStream_t stream) {
  const float* in_x     = (const float*)d_in[0];
  const float* in_pos   = (const float*)d_in[1];
  const float* skip_x   = (const float*)d_in[3];
  const float* skip_pos = (const float*)d_in[4];
  const float* W1       = (const float*)d_in[6];
  const float* bias1    = (const float*)d_in[7];
  const float* W2       = (const float*)d_in[8];
  const float* bias2    = (const float*)d_in[9];

  char* ws = (char*)d_ws;
  // H:   16384*416*2 = 13,631,488
  // h1:  16384*256*2 =  8,388,608
  // W1t:   256*416*2 =    212,992
  // W2t:   256*256*2 =    131,072   (total ~22.4 MB)
  unsigned short* H   = (unsigned short*)(ws);
  unsigned short* h1  = (unsigned short*)(ws + 13631488);
  unsigned short* W1t = (unsigned short*)(ws + 13631488 + 8388608);
  unsigned short* W2t = (unsigned short*)(ws + 13631488 + 8388608 + 212992);

  prep_weights<<<dim3(KPAD), dim3(256), 0, stream>>>(W1, W2, W1t, W2t);
  knn_build_h<<<dim3(MROWS / 4), dim3(256), 0, stream>>>(in_x, in_pos, skip_x,
                                                         skip_pos, H);
  gemm_bt_relu<KPAD, true><<<dim3(MROWS / 128, 2), dim3(256), 0, stream>>>(
      H, W1t, bias1, (void*)h1);
  gemm_bt_relu<256, false><<<dim3(MROWS / 128, 2), dim3(256), 0, stream>>>(
      h1, W2t, bias2, d_out);
}